// Round 4
// baseline (210.574 us; speedup 1.0000x reference)
//
#include <hip/hip_runtime.h>
#include <math.h>

#define NF 128
#define HD 8
#define NPG 2000          // nodes per graph
#define EPB 8000          // edges per sort chunk (4 chunks per graph)
#define LPB 8             // layer blocks per graph
#define LNPB 250          // nodes per layer block
#define FNPB 128          // nodes per feat block (1024 thr)
#define SLOPE 0.01f

__device__ __forceinline__ float lrelu(float v) {
    return v > 0.0f ? v : SLOPE * v;
}
// bf16 helpers: RNE pack, cheap unpack
__device__ __forceinline__ unsigned short f2bf(float f) {
    unsigned int u = __float_as_uint(f);
    return (unsigned short)((u + 0x7FFFu + ((u >> 16) & 1u)) >> 16);
}
__device__ __forceinline__ float bfl(unsigned int p) {
    return __uint_as_float(p << 16);
}
__device__ __forceinline__ float bfh(unsigned int p) {
    return __uint_as_float(p & 0xFFFF0000u);
}
// async global->LDS, 16B per lane; dest = wave-uniform base + lane*16
__device__ __forceinline__ void gload_lds16(const void* g, void* l) {
    __builtin_amdgcn_global_load_lds(
        (const __attribute__((address_space(1))) unsigned int*)g,
        (__attribute__((address_space(3))) unsigned int*)l, 16, 0, 0);
}

// ---------------------------------------------------------------------------
// K1: fused [sort 0..255] + [feat 256..1255]; block 0 additionally zeroes the
// grid-barrier words for K2' (workspace is re-poisoned every iteration).
// ---------------------------------------------------------------------------
__global__ __launch_bounds__(1024) void k_featsort(
    const float* __restrict__ x, const float* __restrict__ W1a,
    const int* __restrict__ ei, unsigned short* __restrict__ t1b,
    unsigned short* __restrict__ gcolb, int* __restrict__ rpc,
    int* __restrict__ bar, int N, int E, int NC)
{
    __shared__ union {
        struct { float tile[FNPB * NF]; float wl[8 * 132]; } f;   // 69.8 KB
        struct { int cnt[NPG]; unsigned int pck[EPB]; int srt[EPB];
                 int wtot[16]; int wpre[16]; } s;                 // 72.1 KB
    } sm;

    const int tid = threadIdx.x;

    if ((int)blockIdx.x < NC) {
        // ---------------- sort chunk b ----------------
        const int b = blockIdx.x;
        if (b == 0 && tid < 4) bar[tid] = 0;   // reset grid-barrier state
        const int g = b >> 2;
        const int lane = tid & 63;
        const int wv = tid >> 6;
        const int nodeBase = g * NPG;
        const int e0 = b * EPB;

        for (int i = tid; i < NPG; i += 1024) sm.s.cnt[i] = 0;
        __syncthreads();

        // single global pass: count + stage packed (dl,src) to LDS
        for (int e = e0 + tid; e < e0 + EPB; e += 1024) {
            int src = ei[e] - nodeBase;               // < 2048
            int dl = ei[E + e] - nodeBase;            // < 2048
            sm.s.pck[e - e0] = ((unsigned int)dl << 11) | (unsigned int)src;
            atomicAdd(&sm.s.cnt[dl], 1);              // native ds_add_u32
        }
        __syncthreads();

        // block-wide exclusive scan; thread t owns pair (2t, 2t+1)
        int c0 = 0, c1 = 0;
        if (tid < 1000) { c0 = sm.s.cnt[2 * tid]; c1 = sm.s.cnt[2 * tid + 1]; }
        int s = c0 + c1;
        int isc = s;
#pragma unroll
        for (int d = 1; d < 64; d <<= 1) {
            int o = __shfl_up(isc, d);
            if (lane >= d) isc += o;
        }
        if (lane == 63) sm.s.wtot[wv] = isc;
        __syncthreads();
        if (wv == 0) {
            int v = (lane < 16) ? sm.s.wtot[lane] : 0;
            int iv = v;
#pragma unroll
            for (int d = 1; d < 16; d <<= 1) {
                int o = __shfl_up(iv, d);
                if (lane >= d) iv += o;
            }
            if (lane < 16) sm.s.wpre[lane] = iv - v;
        }
        __syncthreads();
        int excl = isc - s + sm.s.wpre[wv];

        int* rpb = rpc + (size_t)b * (NPG + 1);
        if (tid < 1000) {
            sm.s.cnt[2 * tid]     = excl;
            sm.s.cnt[2 * tid + 1] = excl + c0;
            rpb[2 * tid]     = excl;
            rpb[2 * tid + 1] = excl + c0;
        }
        if (tid == 0) rpb[NPG] = EPB;
        __syncthreads();

        // scatter pass: all-LDS (pck read -> rtn atomic -> srt write)
        for (int i = tid; i < EPB; i += 1024) {
            unsigned int p = sm.s.pck[i];
            int dl = (int)(p >> 11);
            int src = (int)(p & 2047u);
            int pos = atomicAdd(&sm.s.cnt[dl], 1);    // ds_add_rtn_u32
            sm.s.srt[pos] = src;
        }
        __syncthreads();

        // coalesced dump as ushort (pack 2 per uint)
        unsigned int* dst = (unsigned int*)(gcolb + (size_t)b * EPB);
        for (int i = tid; i < EPB / 2; i += 1024) {
            unsigned int lo = (unsigned int)sm.s.srt[2 * i] & 0xFFFFu;
            unsigned int hi = (unsigned int)sm.s.srt[2 * i + 1] << 16;
            dst[i] = lo | hi;
        }
    } else {
        // ---------------- feat block: 128 nodes ----------------
        const size_t base = (size_t)(blockIdx.x - NC) * FNPB;
        const int lane = tid & 63;
        const int wv6 = tid >> 6;                 // wave id 0..15

        // stage W1a^T: wl[col*132 + k] = W1a[k*8 + col]
        {
            int wcol = tid >> 7;          // 0..7
            int wk   = tid & 127;         // 0..127
            sm.f.wl[wcol * 132 + wk] = W1a[wk * 8 + wcol];
        }

        // x tile: 4096 slots of 16B; slot s=(n,j) sources global chunk
        // (n, j^(n&7)) so reads can use the same XOR (banks spread).
        const float* xg = x + base * NF;
        char* tb = (char*)sm.f.tile;
#pragma unroll
        for (int i = 0; i < 4; ++i) {
            int s = wv6 * 256 + i * 64 + lane;    // linear 16B slot
            int n = s >> 5, j = s & 31;
            gload_lds16(xg + n * NF + ((j ^ (n & 7)) << 2), tb + s * 16);
        }
        __syncthreads();

        const int col   = tid & 7;        // output column
        const int khalf = (tid >> 3) & 1; // k in [khalf*64, khalf*64+64)
        const int np    = tid >> 4;       // node pair 0..63
        const int n0    = np * 2;
        const int ex0 = n0 & 7, ex1 = (n0 + 1) & 7;

        const float*  tf = sm.f.tile;
        const float4* w4 = (const float4*)sm.f.wl;    // col stride 33 float4
        float acc0 = 0.0f, acc1 = 0.0f;
#pragma unroll 4
        for (int i = 0; i < 16; ++i) {
            int k4 = khalf * 16 + i;
            float4 r0 = *(const float4*)(tf + n0 * NF + ((k4 ^ ex0) << 2));
            float4 r1 = *(const float4*)(tf + (n0 + 1) * NF + ((k4 ^ ex1) << 2));
            float4 w  = w4[col * 33 + k4];
            acc0 += r0.x * w.x + r0.y * w.y + r0.z * w.z + r0.w * w.w;
            acc1 += r1.x * w.x + r1.y * w.y + r1.z * w.z + r1.w * w.w;
        }
        // merge k-halves (partner lane differs in bit 3)
        acc0 += __shfl_xor(acc0, 8);
        acc1 += __shfl_xor(acc1, 8);
        if (khalf == 0) {
            t1b[(base + n0) * HD + col]     = f2bf(acc0);
            t1b[(base + n0 + 1) * HD + col] = f2bf(acc1);
        }
    }
}

// ---------------------------------------------------------------------------
// Gather helpers for the fused kernel. LOADSL fills the per-chunk index
// registers (clamped); GATHER_SAVED consumes them (reused across BOTH layers
// — row pointers and neighbor lists are identical between GIN layers).
// ---------------------------------------------------------------------------
#define LOADSL(SL, RS, RE, CP)                                                \
    {                                                                         \
        int cnt = (RE) - (RS);                                                \
        _Pragma("unroll")                                                     \
        for (int j = 0; j < 8; ++j) {                                         \
            int idx = (j < cnt) ? ((RS) + j) : 0;                             \
            SL[j] = CP[idx];                                                  \
        }                                                                     \
    }

#define GATHER_SAVED(SL, RS, RE, CP)                                          \
    {                                                                         \
        int cnt = (RE) - (RS);                                                \
        _Pragma("unroll")                                                     \
        for (int j = 0; j < 8; ++j) {                                         \
            float w = (j < cnt) ? 1.0f : 0.0f;                                \
            uint4 v = tbl[SL[j]];                                             \
            a0 += w * bfl(v.x); a1 += w * bfh(v.x);                           \
            a2 += w * bfl(v.y); a3 += w * bfh(v.y);                           \
            a4 += w * bfl(v.z); a5 += w * bfh(v.z);                           \
            a6 += w * bfl(v.w); a7 += w * bfh(v.w);                           \
        }                                                                     \
        for (int e2 = (RS) + 8; e2 < (RE); ++e2) {                            \
            uint4 v = tbl[CP[e2]];                                            \
            a0 += bfl(v.x); a1 += bfh(v.x);                                   \
            a2 += bfl(v.y); a3 += bfh(v.y);                                   \
            a4 += bfl(v.z); a5 += bfh(v.z);                                   \
            a6 += bfl(v.w); a7 += bfh(v.w);                                   \
        }                                                                     \
    }

// ---------------------------------------------------------------------------
// K2': fused layers 1+2 + finalize. 512 blocks x 512 thr, 2 thr/node.
// Phase 1 = layer 1 (gather t1 from LDS tbl, MLP1, write u to global).
// Device-scope grid barrier (all 512 blocks co-resident: LDS 33.8 KB and
// launch_bounds(512,4) give capacity 4 blocks/CU >= the 2 needed).
// Phase 2 = layer 2 reusing rs/re/sl/colp REGISTERS from phase 1 (zero rpc
// and colp reloads; fp32 self-u), FC1+FC2 partials; last-arriving block
// finalizes log_softmax (old K4).
// ---------------------------------------------------------------------------
__global__ __launch_bounds__(512, 4) void k_l12(
    const unsigned short* __restrict__ t1b, const int* __restrict__ rpc,
    const unsigned short* __restrict__ gcolb, unsigned short* __restrict__ ub,
    const float* __restrict__ b1a, const float* __restrict__ W1b,
    const float* __restrict__ b1b, const float* __restrict__ W2a,
    const float* __restrict__ b2a, const float* __restrict__ W2b,
    const float* __restrict__ b2b, const float* __restrict__ Wf1,
    const float* __restrict__ bf1, const float* __restrict__ Wf2,
    const float* __restrict__ bf2, float* __restrict__ bparts,
    int* __restrict__ bar, float* __restrict__ out)
{
    __shared__ uint4 tbl[2048];       // 32.8 KB (48 pad slots)
    __shared__ float wts[144];        // b1a[8] W1b[64] b1b[8] W2a[64]
    __shared__ float wt2[89];         // b2a[8] W2b[64] b2b[8] Wf1[8] bf1[1]
    __shared__ float red[16];
    __shared__ int lastFlag;

    const int b = blockIdx.x;
    const int g = b >> 3;
    const int q = b & 7;
    const int tid = threadIdx.x;
    const int lane = tid & 63;
    const int wv = tid >> 6;

    if (tid < 144) {
        float v;
        if (tid < 8)       v = b1a[tid];
        else if (tid < 72) v = W1b[tid - 8];
        else if (tid < 80) v = b1b[tid - 72];
        else               v = W2a[tid - 80];
        wts[tid] = v;
    }
    {
        int t2 = tid - 160;           // threads 160..248 load layer-2 weights
        if (t2 >= 0 && t2 < 89) {
            float v;
            if (t2 < 8)       v = b2a[t2];
            else if (t2 < 72) v = W2b[t2 - 8];
            else if (t2 < 80) v = b2b[t2 - 72];
            else if (t2 < 88) v = Wf1[t2 - 80];
            else              v = bf1[0];
            wt2[t2] = v;
        }
    }

    {   // stage t1 table (layer-1 inputs)
        const uint4* src4 = (const uint4*)(t1b + (size_t)g * NPG * HD);
        char* tb = (char*)tbl;
#pragma unroll
        for (int i = 0; i < 4; ++i) {
            int s = wv * 256 + i * 64 + lane;         // 0..2047
            gload_lds16(src4 + s, tb + s * 16);
        }
    }
    __syncthreads();

    // ---------------- phase 1: layer 1 ----------------
    const int node = tid >> 1;            // 0..255 (250 used)
    const int half = tid & 1;
    const int nl = q * LNPB + node;
    const bool act = node < LNPB;
    int rs0 = 0, re0 = 0, rs1 = 0, re1 = 0;
    const unsigned short* cp0 = gcolb;
    const unsigned short* cp1 = gcolb;
    int sl0[8], sl1[8];
    float uu0 = 0, uu1 = 0, uu2 = 0, uu3 = 0, uu4 = 0, uu5 = 0, uu6 = 0, uu7 = 0;

    if (act) {
        const int ch0 = half * 2, ch1 = half * 2 + 1;
        const int* rp0 = rpc + (size_t)((g << 2) + ch0) * (NPG + 1);
        const int* rp1 = rpc + (size_t)((g << 2) + ch1) * (NPG + 1);
        cp0 = gcolb + (size_t)((g << 2) + ch0) * EPB;
        cp1 = gcolb + (size_t)((g << 2) + ch1) * EPB;
        rs0 = rp0[nl]; re0 = rp0[nl + 1];
        rs1 = rp1[nl]; re1 = rp1[nl + 1];
        LOADSL(sl0, rs0, re0, cp0)
        LOADSL(sl1, rs1, re1, cp1)

        float a0 = 0, a1 = 0, a2 = 0, a3 = 0, a4 = 0, a5 = 0, a6 = 0, a7 = 0;
        GATHER_SAVED(sl0, rs0, re0, cp0)
        GATHER_SAVED(sl1, rs1, re1, cp1)
        // merge halves (partner = tid^1, same node)
        a0 += __shfl_xor(a0, 1); a1 += __shfl_xor(a1, 1);
        a2 += __shfl_xor(a2, 1); a3 += __shfl_xor(a3, 1);
        a4 += __shfl_xor(a4, 1); a5 += __shfl_xor(a5, 1);
        a6 += __shfl_xor(a6, 1); a7 += __shfl_xor(a7, 1);

        if (half == 0) {
            uint4 sv = tbl[nl];                       // self t1 feature
            float z[HD];
            z[0] = lrelu(bfl(sv.x) + a0 + wts[0]); z[1] = lrelu(bfh(sv.x) + a1 + wts[1]);
            z[2] = lrelu(bfl(sv.y) + a2 + wts[2]); z[3] = lrelu(bfh(sv.y) + a3 + wts[3]);
            z[4] = lrelu(bfl(sv.z) + a4 + wts[4]); z[5] = lrelu(bfh(sv.z) + a5 + wts[5]);
            z[6] = lrelu(bfl(sv.w) + a6 + wts[6]); z[7] = lrelu(bfh(sv.w) + a7 + wts[7]);

            float h[HD];
#pragma unroll
            for (int j = 0; j < HD; ++j) {
                float acc = wts[72 + j];
#pragma unroll
                for (int c = 0; c < HD; ++c) acc += z[c] * wts[8 + c * HD + j];
                h[j] = lrelu(acc);
            }
            float uu[HD];
#pragma unroll
            for (int j = 0; j < HD; ++j) {
                float acc = 0.0f;
#pragma unroll
                for (int c = 0; c < HD; ++c) acc += h[c] * wts[80 + c * HD + j];
                uu[j] = acc;
            }
            uu0 = uu[0]; uu1 = uu[1]; uu2 = uu[2]; uu3 = uu[3];
            uu4 = uu[4]; uu5 = uu[5]; uu6 = uu[6]; uu7 = uu[7];
            uint4 pk;
            pk.x = (unsigned int)f2bf(uu[0]) | ((unsigned int)f2bf(uu[1]) << 16);
            pk.y = (unsigned int)f2bf(uu[2]) | ((unsigned int)f2bf(uu[3]) << 16);
            pk.z = (unsigned int)f2bf(uu[4]) | ((unsigned int)f2bf(uu[5]) << 16);
            pk.w = (unsigned int)f2bf(uu[6]) | ((unsigned int)f2bf(uu[7]) << 16);
            ((uint4*)ub)[(size_t)g * NPG + nl] = pk;
        }
    }

    // ---------------- grid barrier (all 512 blocks co-resident) ------------
    __syncthreads();
    if (tid == 0) {
        __threadfence();                              // release: u stores visible
        int prev = __hip_atomic_fetch_add(bar, 1, __ATOMIC_ACQ_REL,
                                          __HIP_MEMORY_SCOPE_AGENT);
        if (prev == (int)gridDim.x - 1) {
            __hip_atomic_store(bar + 1, 1, __ATOMIC_RELEASE,
                               __HIP_MEMORY_SCOPE_AGENT);
        } else {
            while (__hip_atomic_load(bar + 1, __ATOMIC_RELAXED,
                                     __HIP_MEMORY_SCOPE_AGENT) == 0)
                __builtin_amdgcn_s_sleep(4);
        }
        __threadfence();                              // acquire: fresh u reads
    }
    __syncthreads();

    {   // restage table with u (layer-2 inputs)
        const uint4* src4 = (const uint4*)(ub + (size_t)g * NPG * HD);
        char* tb = (char*)tbl;
#pragma unroll
        for (int i = 0; i < 4; ++i) {
            int s = wv * 256 + i * 64 + lane;
            gload_lds16(src4 + s, tb + s * 16);
        }
    }
    __syncthreads();

    // ---------------- phase 2: layer 2 + FC1 + FC2 partials ----------------
    float acc0 = 0.0f, acc1 = 0.0f;
    if (act) {
        float a0 = 0, a1 = 0, a2 = 0, a3 = 0, a4 = 0, a5 = 0, a6 = 0, a7 = 0;
        GATHER_SAVED(sl0, rs0, re0, cp0)              // indices reused from regs
        GATHER_SAVED(sl1, rs1, re1, cp1)
        a0 += __shfl_xor(a0, 1); a1 += __shfl_xor(a1, 1);
        a2 += __shfl_xor(a2, 1); a3 += __shfl_xor(a3, 1);
        a4 += __shfl_xor(a4, 1); a5 += __shfl_xor(a5, 1);
        a6 += __shfl_xor(a6, 1); a7 += __shfl_xor(a7, 1);

        if (half == 0) {
            float z[HD];                              // self u in fp32 (regs)
            z[0] = lrelu(uu0 + a0 + wt2[0]); z[1] = lrelu(uu1 + a1 + wt2[1]);
            z[2] = lrelu(uu2 + a2 + wt2[2]); z[3] = lrelu(uu3 + a3 + wt2[3]);
            z[4] = lrelu(uu4 + a4 + wt2[4]); z[5] = lrelu(uu5 + a5 + wt2[5]);
            z[6] = lrelu(uu6 + a6 + wt2[6]); z[7] = lrelu(uu7 + a7 + wt2[7]);

            float svl = wt2[88];
#pragma unroll
            for (int j = 0; j < HD; ++j) {
                float acc = wt2[72 + j];
#pragma unroll
                for (int c = 0; c < HD; ++c) acc += z[c] * wt2[8 + c * HD + j];
                svl += lrelu(acc) * wt2[80 + j];
            }
            float pf = lrelu(svl);
            float2 wf = *(const float2*)(Wf2 + (size_t)nl * 2);
            acc0 = pf * wf.x;
            acc1 = pf * wf.y;
        }
    }

#pragma unroll
    for (int off = 32; off > 0; off >>= 1) {
        acc0 += __shfl_down(acc0, off);
        acc1 += __shfl_down(acc1, off);
    }
    if (lane == 0) { red[wv * 2] = acc0; red[wv * 2 + 1] = acc1; }
    __syncthreads();

    if (tid == 0) {
        float y0 = 0.f, y1 = 0.f;
#pragma unroll
        for (int w = 0; w < 8; ++w) { y0 += red[w * 2]; y1 += red[w * 2 + 1]; }
        *(float2*)(bparts + (size_t)b * 2) = make_float2(y0, y1);
        __threadfence();                              // bparts visible
        int prev = __hip_atomic_fetch_add(bar + 2, 1, __ATOMIC_ACQ_REL,
                                          __HIP_MEMORY_SCOPE_AGENT);
        lastFlag = (prev == (int)gridDim.x - 1);
        if (lastFlag) __threadfence();                // acquire for bparts reads
    }
    __syncthreads();

    // last-arriving block finalizes (old K4): one lane per graph
    if (lastFlag && tid < 64) {
        const int gg = tid;
        float y0 = bf2[0], y1 = bf2[1];
#pragma unroll
        for (int p = 0; p < LPB; ++p) {
            float2 v = *(const float2*)(bparts + (size_t)(gg * LPB + p) * 2);
            y0 += v.x; y1 += v.y;
        }
        float m = fmaxf(y0, y1);
        float lse = m + logf(expf(y0 - m) + expf(y1 - m));
        out[gg * 2 + 0] = y0 - lse;
        out[gg * 2 + 1] = y1 - lse;
    }
}

// ---------------------------------------------------------------------------
extern "C" void kernel_launch(void* const* d_in, const int* in_sizes, int n_in,
                              void* d_out, int out_size, void* d_ws, size_t ws_size,
                              hipStream_t stream) {
    const float* x   = (const float*)d_in[0];
    const int*   ei  = (const int*)  d_in[1];
    const float* W1a = (const float*)d_in[3];
    const float* b1a = (const float*)d_in[4];
    const float* W1b = (const float*)d_in[5];
    const float* b1b = (const float*)d_in[6];
    const float* W2a = (const float*)d_in[7];
    const float* b2a = (const float*)d_in[8];
    const float* W2b = (const float*)d_in[9];
    const float* b2b = (const float*)d_in[10];
    const float* Wf1 = (const float*)d_in[11];
    const float* bf1 = (const float*)d_in[12];
    const float* Wf2 = (const float*)d_in[13];
    const float* bf2 = (const float*)d_in[14];

    int N   = in_sizes[0] / NF;        // 128000
    int E   = in_sizes[1] / 2;         // 2048000
    int Bn  = N / NPG;                 // 64 graphs
    int NC  = Bn * 4;                  // 256 chunks

    // workspace carve-up (16B-aligned sections)
    unsigned short* t1b   = (unsigned short*)d_ws;              // N*8 bf16  2.0 MB
    unsigned short* ubuf  = t1b + (size_t)N * HD;               // N*8 bf16  2.0 MB
    unsigned short* gcolb = ubuf + (size_t)N * HD;              // E ushort  4.1 MB
    int*            rpc   = (int*)(gcolb + (size_t)E);          // NC*(NPG+1) 2.0 MB
    float*          bparts= (float*)(rpc + (size_t)NC * (NPG + 1) + 16); // 512*2
    int*            bar   = (int*)(bparts + 1024 + 16);         // barrier words

    k_featsort<<<NC + N / FNPB, 1024, 0, stream>>>(x, W1a, ei, t1b, gcolb, rpc,
                                                   bar, N, E, NC);
    k_l12<<<Bn * LPB, 512, 0, stream>>>(t1b, rpc, gcolb, ubuf,
                                        b1a, W1b, b1b, W2a,
                                        b2a, W2b, b2b, Wf1, bf1, Wf2, bf2,
                                        bparts, bar, (float*)d_out);
}

// Round 5
// 161.536 us; speedup vs baseline: 1.3036x; 1.3036x over previous
//
#include <hip/hip_runtime.h>
#include <math.h>

#define NF 128
#define HD 8
#define NPG 2000          // nodes per graph
#define EPB 8000          // edges per sort chunk (4 chunks per graph)
#define LPB 8             // layer blocks per graph
#define LNPB 250          // nodes per layer block
#define FNPB 128          // nodes per feat block (1024 thr)
#define SLOPE 0.01f
#define PADIDX 2000u      // padded-slot index -> tbl[2000] == 0

__device__ __forceinline__ float lrelu(float v) {
    return v > 0.0f ? v : SLOPE * v;
}
// bf16 helpers: RNE pack, cheap unpack
__device__ __forceinline__ unsigned short f2bf(float f) {
    unsigned int u = __float_as_uint(f);
    return (unsigned short)((u + 0x7FFFu + ((u >> 16) & 1u)) >> 16);
}
__device__ __forceinline__ float bfl(unsigned int p) {
    return __uint_as_float(p << 16);
}
__device__ __forceinline__ float bfh(unsigned int p) {
    return __uint_as_float(p & 0xFFFF0000u);
}
// async global->LDS, 16B per lane; dest = wave-uniform base + lane*16
__device__ __forceinline__ void gload_lds16(const void* g, void* l) {
    __builtin_amdgcn_global_load_lds(
        (const __attribute__((address_space(1))) unsigned int*)g,
        (__attribute__((address_space(3))) unsigned int*)l, 16, 0, 0);
}

// pack first 8 CSR entries of a node into 8 ushorts (pad = PADIDX);
// bit15 of slot0 flags degree>8 (tail served from CSR).
__device__ __forceinline__ uint4 packpad(const int* srt, int st, int cnt) {
    unsigned int w[4];
#pragma unroll
    for (int h = 0; h < 4; ++h) {
        unsigned int lo = (2 * h     < cnt) ? (unsigned int)srt[st + 2 * h]     : PADIDX;
        unsigned int hi = (2 * h + 1 < cnt) ? (unsigned int)srt[st + 2 * h + 1] : PADIDX;
        w[h] = lo | (hi << 16);
    }
    if (cnt > 8) w[0] |= 0x8000u;
    return make_uint4(w[0], w[1], w[2], w[3]);
}

// ---------------------------------------------------------------------------
// K1: fused [sort 0..255: count/scan/scatter in LDS; dumps CSR (gcolb,rpc)
//      AND node-indexed 8-wide padded adjacency (pnb)] +
//     [feat 256..1255: 128 nodes; thread=(node-pair, col, k-half)].
// ---------------------------------------------------------------------------
__global__ __launch_bounds__(1024) void k_featsort(
    const float* __restrict__ x, const float* __restrict__ W1a,
    const int* __restrict__ ei, unsigned short* __restrict__ t1b,
    unsigned short* __restrict__ gcolb, int* __restrict__ rpc,
    unsigned short* __restrict__ pnb, int N, int E, int NC)
{
    __shared__ union {
        struct { float tile[FNPB * NF]; float wl[8 * 132]; } f;   // 69.8 KB
        struct { int cnt[NPG]; unsigned int pck[EPB]; int srt[EPB];
                 int wtot[16]; int wpre[16]; } s;                 // 72.1 KB
    } sm;

    const int tid = threadIdx.x;

    if ((int)blockIdx.x < NC) {
        // ---------------- sort chunk b ----------------
        const int b = blockIdx.x;
        const int g = b >> 2;
        const int lane = tid & 63;
        const int wv = tid >> 6;
        const int nodeBase = g * NPG;
        const int e0 = b * EPB;

        for (int i = tid; i < NPG; i += 1024) sm.s.cnt[i] = 0;
        __syncthreads();

        // single global pass: count + stage packed (dl,src) to LDS
        for (int e = e0 + tid; e < e0 + EPB; e += 1024) {
            int src = ei[e] - nodeBase;               // < 2048
            int dl = ei[E + e] - nodeBase;            // < 2048
            sm.s.pck[e - e0] = ((unsigned int)dl << 11) | (unsigned int)src;
            atomicAdd(&sm.s.cnt[dl], 1);              // native ds_add_u32
        }
        __syncthreads();

        // block-wide exclusive scan; thread t owns pair (2t, 2t+1)
        int c0 = 0, c1 = 0;
        if (tid < 1000) { c0 = sm.s.cnt[2 * tid]; c1 = sm.s.cnt[2 * tid + 1]; }
        int s = c0 + c1;
        int isc = s;
#pragma unroll
        for (int d = 1; d < 64; d <<= 1) {
            int o = __shfl_up(isc, d);
            if (lane >= d) isc += o;
        }
        if (lane == 63) sm.s.wtot[wv] = isc;
        __syncthreads();
        if (wv == 0) {
            int v = (lane < 16) ? sm.s.wtot[lane] : 0;
            int iv = v;
#pragma unroll
            for (int d = 1; d < 16; d <<= 1) {
                int o = __shfl_up(iv, d);
                if (lane >= d) iv += o;
            }
            if (lane < 16) sm.s.wpre[lane] = iv - v;
        }
        __syncthreads();
        int excl = isc - s + sm.s.wpre[wv];

        int* rpb = rpc + (size_t)b * (NPG + 1);
        if (tid < 1000) {
            sm.s.cnt[2 * tid]     = excl;
            sm.s.cnt[2 * tid + 1] = excl + c0;
            rpb[2 * tid]     = excl;
            rpb[2 * tid + 1] = excl + c0;
        }
        if (tid == 0) rpb[NPG] = EPB;
        __syncthreads();

        // scatter pass: all-LDS (pck read -> rtn atomic -> srt write)
        for (int i = tid; i < EPB; i += 1024) {
            unsigned int p = sm.s.pck[i];
            int dl = (int)(p >> 11);
            int src = (int)(p & 2047u);
            int pos = atomicAdd(&sm.s.cnt[dl], 1);    // ds_add_rtn_u32
            sm.s.srt[pos] = src;
        }
        __syncthreads();

        // coalesced CSR dump as ushort (pack 2 per uint) — tails read this
        unsigned int* dst = (unsigned int*)(gcolb + (size_t)b * EPB);
        for (int i = tid; i < EPB / 2; i += 1024) {
            unsigned int lo = (unsigned int)sm.s.srt[2 * i] & 0xFFFFu;
            unsigned int hi = (unsigned int)sm.s.srt[2 * i + 1] << 16;
            dst[i] = lo | hi;
        }

        // 8-wide padded adjacency dump (fast gather path): node-indexed,
        // directly addressable, no row pointers needed.
        if (tid < 1000) {
            uint4* pdst = (uint4*)(pnb + (size_t)b * NPG * 8);
            pdst[2 * tid]     = packpad(sm.s.srt, excl, c0);
            pdst[2 * tid + 1] = packpad(sm.s.srt, excl + c0, c1);
        }
    } else {
        // ---------------- feat block: 128 nodes ----------------
        const size_t base = (size_t)(blockIdx.x - NC) * FNPB;
        const int lane = tid & 63;
        const int wv6 = tid >> 6;                 // wave id 0..15

        // stage W1a^T: wl[col*132 + k] = W1a[k*8 + col]
        {
            int wcol = tid >> 7;          // 0..7
            int wk   = tid & 127;         // 0..127
            sm.f.wl[wcol * 132 + wk] = W1a[wk * 8 + wcol];
        }

        // x tile: 4096 slots of 16B; slot s=(n,j) sources global chunk
        // (n, j^(n&7)) so reads can use the same XOR (banks spread).
        const float* xg = x + base * NF;
        char* tb = (char*)sm.f.tile;
#pragma unroll
        for (int i = 0; i < 4; ++i) {
            int s = wv6 * 256 + i * 64 + lane;    // linear 16B slot
            int n = s >> 5, j = s & 31;
            gload_lds16(xg + n * NF + ((j ^ (n & 7)) << 2), tb + s * 16);
        }
        __syncthreads();

        const int col   = tid & 7;        // output column
        const int khalf = (tid >> 3) & 1; // k in [khalf*64, khalf*64+64)
        const int np    = tid >> 4;       // node pair 0..63
        const int n0    = np * 2;
        const int ex0 = n0 & 7, ex1 = (n0 + 1) & 7;

        const float*  tf = sm.f.tile;
        const float4* w4 = (const float4*)sm.f.wl;    // col stride 33 float4
        float acc0 = 0.0f, acc1 = 0.0f;
#pragma unroll 4
        for (int i = 0; i < 16; ++i) {
            int k4 = khalf * 16 + i;
            float4 r0 = *(const float4*)(tf + n0 * NF + ((k4 ^ ex0) << 2));
            float4 r1 = *(const float4*)(tf + (n0 + 1) * NF + ((k4 ^ ex1) << 2));
            float4 w  = w4[col * 33 + k4];
            acc0 += r0.x * w.x + r0.y * w.y + r0.z * w.z + r0.w * w.w;
            acc1 += r1.x * w.x + r1.y * w.y + r1.z * w.z + r1.w * w.w;
        }
        // merge k-halves (partner lane differs in bit 3)
        acc0 += __shfl_xor(acc0, 8);
        acc1 += __shfl_xor(acc1, 8);
        if (khalf == 0) {
            t1b[(base + n0) * HD + col]     = f2bf(acc0);
            t1b[(base + n0 + 1) * HD + col] = f2bf(acc1);
        }
    }
}

// ---------------------------------------------------------------------------
// Fast gather from padded adjacency word-pack: 8 unconditional LDS gathers
// (pads hit the zeroed slot tbl[2000]); identical summation order to CSR.
// ---------------------------------------------------------------------------
#define GATHER_PAD(PW)                                                        \
    {                                                                         \
        unsigned int w_[4] = {PW.x, PW.y, PW.z, PW.w};                        \
        _Pragma("unroll")                                                     \
        for (int h = 0; h < 4; ++h) {                                         \
            uint4 v = tbl[w_[h] & 2047u];                                     \
            a0 += bfl(v.x); a1 += bfh(v.x);                                   \
            a2 += bfl(v.y); a3 += bfh(v.y);                                   \
            a4 += bfl(v.z); a5 += bfh(v.z);                                   \
            a6 += bfl(v.w); a7 += bfh(v.w);                                   \
            uint4 v2 = tbl[(w_[h] >> 16) & 2047u];                            \
            a0 += bfl(v2.x); a1 += bfh(v2.x);                                 \
            a2 += bfl(v2.y); a3 += bfh(v2.y);                                 \
            a4 += bfl(v2.z); a5 += bfh(v2.z);                                 \
            a6 += bfl(v2.w); a7 += bfh(v2.w);                                 \
        }                                                                     \
    }

// rare (P~2%) degree>8 tail via CSR
#define TAIL_PAD(PW, CH)                                                      \
    if (PW.x & 0x8000u) {                                                     \
        const int* rpb_ = rpc + (size_t)((g << 2) + (CH)) * (NPG + 1);        \
        const unsigned short* cp_ = gcolb + (size_t)((g << 2) + (CH)) * EPB;  \
        int rs_ = rpb_[nl], re_ = rpb_[nl + 1];                               \
        for (int e2 = rs_ + 8; e2 < re_; ++e2) {                              \
            uint4 v = tbl[cp_[e2]];                                           \
            a0 += bfl(v.x); a1 += bfh(v.x);                                   \
            a2 += bfl(v.y); a3 += bfh(v.y);                                   \
            a4 += bfl(v.z); a5 += bfh(v.z);                                   \
            a6 += bfl(v.w); a7 += bfh(v.w);                                   \
        }                                                                     \
    }

#define MERGE2()                                                              \
    a0 += __shfl_xor(a0, 1); a1 += __shfl_xor(a1, 1);                         \
    a2 += __shfl_xor(a2, 1); a3 += __shfl_xor(a3, 1);                         \
    a4 += __shfl_xor(a4, 1); a5 += __shfl_xor(a5, 1);                         \
    a6 += __shfl_xor(a6, 1); a7 += __shfl_xor(a7, 1);

// ---------------------------------------------------------------------------
// K2: layer 1. 8 blocks/graph x 512 thr. 2 threads/node, one padded-adj
// 16B load per chunk (no rpc / colp chain), shfl_xor(1) merge, half-0 MLP1.
// ---------------------------------------------------------------------------
__global__ __launch_bounds__(512) void k_l1(
    const unsigned short* __restrict__ t1b, const int* __restrict__ rpc,
    const unsigned short* __restrict__ gcolb,
    const unsigned short* __restrict__ pnb, unsigned short* __restrict__ ub,
    const float* __restrict__ b1a, const float* __restrict__ W1b,
    const float* __restrict__ b1b, const float* __restrict__ W2a)
{
    __shared__ uint4 tbl[2048];       // 32.8 KB; tbl[2000] zeroed (pad slot)
    __shared__ float wts[144];        // b1a[8] W1b[64] b1b[8] W2a[64]

    const int b = blockIdx.x;
    const int g = b >> 3;
    const int q = b & 7;
    const int tid = threadIdx.x;
    const int lane = tid & 63;
    const int wv = tid >> 6;

    if (tid < 144) {
        float v;
        if (tid < 8)       v = b1a[tid];
        else if (tid < 72) v = W1b[tid - 8];
        else if (tid < 80) v = b1b[tid - 72];
        else               v = W2a[tid - 80];
        wts[tid] = v;
    }

    {
        const uint4* src4 = (const uint4*)(t1b + (size_t)g * NPG * HD);
        char* tb = (char*)tbl;
#pragma unroll
        for (int i = 0; i < 4; ++i) {
            int s = wv * 256 + i * 64 + lane;         // 0..2047
            gload_lds16(src4 + s, tb + s * 16);
        }
    }
    __syncthreads();
    if (tid == 0) tbl[PADIDX] = make_uint4(0, 0, 0, 0);
    __syncthreads();

    if (tid < 2 * LNPB) {
        const int node = tid >> 1;            // 0..249
        const int half = tid & 1;
        const int nl = q * LNPB + node;
        const int ch0 = half * 2, ch1 = half * 2 + 1;
        const uint4* pn0 = (const uint4*)pnb + (size_t)((g << 2) + ch0) * NPG;
        const uint4* pn1 = (const uint4*)pnb + (size_t)((g << 2) + ch1) * NPG;
        uint4 p0 = pn0[nl];
        uint4 p1 = pn1[nl];

        float a0 = 0, a1 = 0, a2 = 0, a3 = 0, a4 = 0, a5 = 0, a6 = 0, a7 = 0;
        GATHER_PAD(p0) GATHER_PAD(p1)
        TAIL_PAD(p0, ch0) TAIL_PAD(p1, ch1)
        MERGE2()

        if (half == 0) {
            uint4 sv = tbl[nl];                       // self feature
            float z[HD];
            z[0] = lrelu(bfl(sv.x) + a0 + wts[0]); z[1] = lrelu(bfh(sv.x) + a1 + wts[1]);
            z[2] = lrelu(bfl(sv.y) + a2 + wts[2]); z[3] = lrelu(bfh(sv.y) + a3 + wts[3]);
            z[4] = lrelu(bfl(sv.z) + a4 + wts[4]); z[5] = lrelu(bfh(sv.z) + a5 + wts[5]);
            z[6] = lrelu(bfl(sv.w) + a6 + wts[6]); z[7] = lrelu(bfh(sv.w) + a7 + wts[7]);

            float h[HD];
#pragma unroll
            for (int j = 0; j < HD; ++j) {
                float acc = wts[72 + j];
#pragma unroll
                for (int c = 0; c < HD; ++c) acc += z[c] * wts[8 + c * HD + j];
                h[j] = lrelu(acc);
            }
            float uu[HD];
#pragma unroll
            for (int j = 0; j < HD; ++j) {
                float acc = 0.0f;
#pragma unroll
                for (int c = 0; c < HD; ++c) acc += h[c] * wts[80 + c * HD + j];
                uu[j] = acc;
            }
            uint4 pk;
            pk.x = (unsigned int)f2bf(uu[0]) | ((unsigned int)f2bf(uu[1]) << 16);
            pk.y = (unsigned int)f2bf(uu[2]) | ((unsigned int)f2bf(uu[3]) << 16);
            pk.z = (unsigned int)f2bf(uu[4]) | ((unsigned int)f2bf(uu[5]) << 16);
            pk.w = (unsigned int)f2bf(uu[6]) | ((unsigned int)f2bf(uu[7]) << 16);
            ((uint4*)ub)[(size_t)g * NPG + nl] = pk;
        }
    }
}

// ---------------------------------------------------------------------------
// K3: layer 2, same structure over ub; MLP2 + FC1 + FC2 partials;
// plain-store per-block partial. k_fin finalizes.
// ---------------------------------------------------------------------------
__global__ __launch_bounds__(512) void k_l2(
    const unsigned short* __restrict__ ub, const int* __restrict__ rpc,
    const unsigned short* __restrict__ gcolb,
    const unsigned short* __restrict__ pnb,
    const float* __restrict__ b2a, const float* __restrict__ W2b,
    const float* __restrict__ b2b, const float* __restrict__ Wf1,
    const float* __restrict__ bf1, const float* __restrict__ Wf2,
    float* __restrict__ bparts)
{
    __shared__ uint4 tbl[2048];       // 32.8 KB; tbl[2000] zeroed (pad slot)
    __shared__ float wts[89];         // b2a[8] W2b[64] b2b[8] Wf1[8] bf1[1]
    __shared__ float red[16];

    const int b = blockIdx.x;
    const int g = b >> 3;
    const int q = b & 7;
    const int tid = threadIdx.x;
    const int lane = tid & 63;
    const int wv = tid >> 6;

    if (tid < 89) {
        float v;
        if (tid < 8)       v = b2a[tid];
        else if (tid < 72) v = W2b[tid - 8];
        else if (tid < 80) v = b2b[tid - 72];
        else if (tid < 88) v = Wf1[tid - 80];
        else               v = bf1[0];
        wts[tid] = v;
    }

    {
        const uint4* src4 = (const uint4*)(ub + (size_t)g * NPG * HD);
        char* tb = (char*)tbl;
#pragma unroll
        for (int i = 0; i < 4; ++i) {
            int s = wv * 256 + i * 64 + lane;         // 0..2047
            gload_lds16(src4 + s, tb + s * 16);
        }
    }
    __syncthreads();
    if (tid == 0) tbl[PADIDX] = make_uint4(0, 0, 0, 0);
    __syncthreads();

    float acc0 = 0.0f, acc1 = 0.0f;
    if (tid < 2 * LNPB) {
        const int node = tid >> 1;
        const int half = tid & 1;
        const int nl = q * LNPB + node;
        const int ch0 = half * 2, ch1 = half * 2 + 1;
        const uint4* pn0 = (const uint4*)pnb + (size_t)((g << 2) + ch0) * NPG;
        const uint4* pn1 = (const uint4*)pnb + (size_t)((g << 2) + ch1) * NPG;
        uint4 p0 = pn0[nl];
        uint4 p1 = pn1[nl];

        float a0 = 0, a1 = 0, a2 = 0, a3 = 0, a4 = 0, a5 = 0, a6 = 0, a7 = 0;
        GATHER_PAD(p0) GATHER_PAD(p1)
        TAIL_PAD(p0, ch0) TAIL_PAD(p1, ch1)
        MERGE2()

        if (half == 0) {
            uint4 sv = tbl[nl];
            float z[HD];
            z[0] = lrelu(bfl(sv.x) + a0 + wts[0]); z[1] = lrelu(bfh(sv.x) + a1 + wts[1]);
            z[2] = lrelu(bfl(sv.y) + a2 + wts[2]); z[3] = lrelu(bfh(sv.y) + a3 + wts[3]);
            z[4] = lrelu(bfl(sv.z) + a4 + wts[4]); z[5] = lrelu(bfh(sv.z) + a5 + wts[5]);
            z[6] = lrelu(bfl(sv.w) + a6 + wts[6]); z[7] = lrelu(bfh(sv.w) + a7 + wts[7]);

            float svl = wts[88];
#pragma unroll
            for (int j = 0; j < HD; ++j) {
                float acc = wts[72 + j];
#pragma unroll
                for (int c = 0; c < HD; ++c) acc += z[c] * wts[8 + c * HD + j];
                svl += lrelu(acc) * wts[80 + j];
            }
            float pf = lrelu(svl);
            float2 wf = *(const float2*)(Wf2 + (size_t)nl * 2);
            acc0 = pf * wf.x;
            acc1 = pf * wf.y;
        }
    }

#pragma unroll
    for (int off = 32; off > 0; off >>= 1) {
        acc0 += __shfl_down(acc0, off);
        acc1 += __shfl_down(acc1, off);
    }
    if (lane == 0) { red[wv * 2] = acc0; red[wv * 2 + 1] = acc1; }
    __syncthreads();

    if (tid == 0) {
        float y0 = 0.f, y1 = 0.f;
#pragma unroll
        for (int w = 0; w < 8; ++w) { y0 += red[w * 2]; y1 += red[w * 2 + 1]; }
        *(float2*)(bparts + (size_t)b * 2) = make_float2(y0, y1);
    }
}

// ---------------------------------------------------------------------------
// K4: finalize — one thread per graph sums 8 block partials, log_softmax.
// ---------------------------------------------------------------------------
__global__ __launch_bounds__(64) void k_fin(const float* __restrict__ bparts,
                                            const float* __restrict__ bf2,
                                            float* __restrict__ out, int Bn) {
    int g = threadIdx.x;
    if (g >= Bn) return;
    float y0 = bf2[0], y1 = bf2[1];
#pragma unroll
    for (int b = 0; b < LPB; ++b) {
        float2 v = *(const float2*)(bparts + (size_t)(g * LPB + b) * 2);
        y0 += v.x; y1 += v.y;
    }
    float m = fmaxf(y0, y1);
    float lse = m + logf(expf(y0 - m) + expf(y1 - m));
    out[g * 2 + 0] = y0 - lse;
    out[g * 2 + 1] = y1 - lse;
}

// ---------------------------------------------------------------------------
extern "C" void kernel_launch(void* const* d_in, const int* in_sizes, int n_in,
                              void* d_out, int out_size, void* d_ws, size_t ws_size,
                              hipStream_t stream) {
    const float* x   = (const float*)d_in[0];
    const int*   ei  = (const int*)  d_in[1];
    const float* W1a = (const float*)d_in[3];
    const float* b1a = (const float*)d_in[4];
    const float* W1b = (const float*)d_in[5];
    const float* b1b = (const float*)d_in[6];
    const float* W2a = (const float*)d_in[7];
    const float* b2a = (const float*)d_in[8];
    const float* W2b = (const float*)d_in[9];
    const float* b2b = (const float*)d_in[10];
    const float* Wf1 = (const float*)d_in[11];
    const float* bf1 = (const float*)d_in[12];
    const float* Wf2 = (const float*)d_in[13];
    const float* bf2 = (const float*)d_in[14];

    int N   = in_sizes[0] / NF;        // 128000
    int E   = in_sizes[1] / 2;         // 2048000
    int Bn  = N / NPG;                 // 64 graphs
    int NC  = Bn * 4;                  // 256 chunks

    // workspace carve-up (16B-aligned sections)
    unsigned short* t1b   = (unsigned short*)d_ws;              // N*8 bf16  2.0 MB
    unsigned short* ubuf  = t1b + (size_t)N * HD;               // N*8 bf16  2.0 MB
    unsigned short* gcolb = ubuf + (size_t)N * HD;              // E ushort  4.1 MB
    int*            rpc   = (int*)(gcolb + (size_t)E);          // NC*(NPG+1) 2.0 MB
    float*          bparts= (float*)(rpc + (size_t)NC * (NPG + 1) + 16); // 512*2
    unsigned short* pnb   = (unsigned short*)(bparts + 1024 + 16); // NC*NPG*8 8.2 MB

    k_featsort<<<NC + N / FNPB, 1024, 0, stream>>>(x, W1a, ei, t1b, gcolb, rpc,
                                                   pnb, N, E, NC);
    k_l1 <<<Bn * LPB, 512, 0, stream>>>(t1b, rpc, gcolb, pnb, ubuf,
                                        b1a, W1b, b1b, W2a);
    k_l2 <<<Bn * LPB, 512, 0, stream>>>(ubuf, rpc, gcolb, pnb,
                                        b2a, W2b, b2b, Wf1, bf1, Wf2, bparts);
    k_fin<<<1, 64, 0, stream>>>(bparts, bf2, (float*)d_out, Bn);
}